// Round 3
// baseline (2046.173 us; speedup 1.0000x reference)
//
#include <hip/hip_runtime.h>
#include <hip/hip_bf16.h>
#include <hip/hip_fp16.h>

typedef _Float16 f16x8 __attribute__((ext_vector_type(8)));
typedef float    f32x4 __attribute__((ext_vector_type(4)));

#define T_LEN 2048
#define T_CHUNK 1024

__device__ inline f32x4 vfma4(f32x4 a, f32x4 b, f32x4 c) {
#if __has_builtin(__builtin_elementwise_fma)
  return __builtin_elementwise_fma(a, b, c);
#else
  return a * b + c;
#endif
}

// ---------------- k1: dwconv + BN + ReLU + residual + pointwise -> hpw f32 [t_local*64+b][128]
__global__ __launch_bounds__(256) void k1_front(
    const float* __restrict__ x, const float* __restrict__ dw_w, const float* __restrict__ dw_b,
    const float* __restrict__ bn_g, const float* __restrict__ bn_b, const float* __restrict__ bn_m,
    const float* __restrict__ bn_v, const float* __restrict__ pw_w, const float* __restrict__ pw_b,
    float* __restrict__ hpw, int tc0) {
  __shared__ float xs[64][130];   // global t0-1 .. t0+128
  __shared__ float ys[64][128];
  __shared__ float wT[64][128];   // wT[c][o] = pw_w[o][c]
  __shared__ float4 sc[64];       // folded dw+bn params
  const int b = blockIdx.y;
  const int t0l = blockIdx.x * 128;       // local within chunk
  const int t0 = tc0 + t0l;               // global
  const int tid = threadIdx.x;

  for (int idx = tid; idx < 64 * 130; idx += 256) {
    int c = idx / 130, tt = idx % 130;
    int gt = t0 + tt - 1;
    xs[c][tt] = (gt >= 0 && gt < T_LEN) ? x[((size_t)b * 64 + c) * T_LEN + gt] : 0.f;
  }
  for (int idx = tid; idx < 64 * 128; idx += 256) {
    int o = idx & 127, c = idx >> 7;
    wT[c][o] = pw_w[o * 64 + c];
  }
  if (tid < 64) {
    int c = tid;
    float inv = bn_g[c] * rsqrtf(bn_v[c] + 1e-5f);
    sc[c] = make_float4(dw_w[c * 3 + 0] * inv, dw_w[c * 3 + 1] * inv, dw_w[c * 3 + 2] * inv,
                        (dw_b[c] - bn_m[c]) * inv + bn_b[c]);
  }
  __syncthreads();
  for (int idx = tid; idx < 64 * 128; idx += 256) {
    int c = idx >> 7, j = idx & 127;
    float4 s = sc[c];
    float v = s.x * xs[c][j] + s.y * xs[c][j + 1] + s.z * xs[c][j + 2] + s.w;
    ys[c][j] = fmaxf(v, 0.f) + xs[c][j + 1];
  }
  __syncthreads();
  // pointwise: thread owns output channel o, 64 t's
  const int o = tid & 127, tg = tid >> 7, tb = tg * 64;
  float acc[64];
#pragma unroll
  for (int i = 0; i < 64; ++i) acc[i] = 0.f;
  for (int c = 0; c < 64; ++c) {
    float w = wT[c][o];
#pragma unroll
    for (int i = 0; i < 64; ++i) acc[i] = fmaf(w, ys[c][tb + i], acc[i]);
  }
  float pb = pw_b[o];
#pragma unroll
  for (int i = 0; i < 64; ++i) {
    hpw[((size_t)(t0l + tb + i) * 64 + b) * 128 + o] = acc[i] + pb;
  }
}

// ---------------- k2: gx[m][512] = hpw @ w_ih^T + (b_ih+b_hh), split-f16 MFMA (f32-accurate)
// x = hi + lo/2048, with hi=(f16)x, lo=(f16)((x-hi)*2048): products
// x*y ~= hi*hi + (hi*lo' + lo'*hi)/2048  (lo'*lo' ~ 2^-22, dropped)
__global__ __launch_bounds__(256) void k2_gx(
    const float* __restrict__ hpw, const float* __restrict__ w_ih,
    const float* __restrict__ b_ih, const float* __restrict__ b_hh, float* __restrict__ gx) {
  __shared__ __align__(16) _Float16 As_hi[128 * 128];
  __shared__ __align__(16) _Float16 As_lo[128 * 128];
  __shared__ __align__(16) _Float16 Bs_hi[128 * 128];
  __shared__ __align__(16) _Float16 Bs_lo[128 * 128];
  const int m0 = blockIdx.x * 128;
  const int n0 = blockIdx.y * 128;
  const int tid = threadIdx.x;

  // stage A (hpw rows, f32) -> hi/lo f16, XOR-swizzled 16B units: u' = u ^ (row&7)
#pragma unroll
  for (int it = 0; it < 8; ++it) {
    int idx = it * 256 + tid;
    int r = idx >> 4, u = idx & 15;
    const float* src = hpw + ((size_t)(m0 + r) << 7) + u * 8;
    f16x8 hi, lo;
#pragma unroll
    for (int j = 0; j < 8; ++j) {
      float v = src[j];
      _Float16 h = (_Float16)v;
      hi[j] = h;
      lo[j] = (_Float16)((v - (float)h) * 2048.0f);
    }
    int du = (u ^ (r & 7)) * 16;
    *(f16x8*)((char*)As_hi + r * 256 + du) = hi;
    *(f16x8*)((char*)As_lo + r * 256 + du) = lo;
  }
  // stage B = w_ih rows (N-major, K contiguous)
#pragma unroll
  for (int it = 0; it < 8; ++it) {
    int idx = it * 256 + tid;
    int r = idx >> 4, u = idx & 15;
    const float* src = w_ih + (size_t)(n0 + r) * 128 + u * 8;
    f16x8 hi, lo;
#pragma unroll
    for (int j = 0; j < 8; ++j) {
      float v = src[j];
      _Float16 h = (_Float16)v;
      hi[j] = h;
      lo[j] = (_Float16)((v - (float)h) * 2048.0f);
    }
    int du = (u ^ (r & 7)) * 16;
    *(f16x8*)((char*)Bs_hi + r * 256 + du) = hi;
    *(f16x8*)((char*)Bs_lo + r * 256 + du) = lo;
  }
  __syncthreads();

  const int lane = tid & 63, wv = tid >> 6;
  const int wm = (wv >> 1) * 64, wn = (wv & 1) * 64;
  f32x4 acc[4][4] = {};   // hi*hi
  f32x4 accc[4][4] = {};  // hi*lo' + lo'*hi  (carries x2048)
#pragma unroll
  for (int kk = 0; kk < 4; ++kk) {
    f16x8 ah[4], al[4], bh[4], bl[4];
#pragma unroll
    for (int mi = 0; mi < 4; ++mi) {
      int row = wm + mi * 16 + (lane & 15);
      int u = kk * 4 + (lane >> 4);
      int off = row * 256 + ((u ^ (row & 7)) * 16);
      ah[mi] = *(const f16x8*)((const char*)As_hi + off);
      al[mi] = *(const f16x8*)((const char*)As_lo + off);
    }
#pragma unroll
    for (int ni = 0; ni < 4; ++ni) {
      int row = wn + ni * 16 + (lane & 15);
      int u = kk * 4 + (lane >> 4);
      int off = row * 256 + ((u ^ (row & 7)) * 16);
      bh[ni] = *(const f16x8*)((const char*)Bs_hi + off);
      bl[ni] = *(const f16x8*)((const char*)Bs_lo + off);
    }
#pragma unroll
    for (int mi = 0; mi < 4; ++mi)
#pragma unroll
      for (int ni = 0; ni < 4; ++ni) {
        acc[mi][ni]  = __builtin_amdgcn_mfma_f32_16x16x32_f16(ah[mi], bh[ni], acc[mi][ni], 0, 0, 0);
        accc[mi][ni] = __builtin_amdgcn_mfma_f32_16x16x32_f16(ah[mi], bl[ni], accc[mi][ni], 0, 0, 0);
        accc[mi][ni] = __builtin_amdgcn_mfma_f32_16x16x32_f16(al[mi], bh[ni], accc[mi][ni], 0, 0, 0);
      }
  }
  // epilogue: C row=(lane>>4)*4+j, col=lane&15 within each 16x16 tile
  const float ks = 1.0f / 2048.0f;
#pragma unroll
  for (int ni = 0; ni < 4; ++ni) {
    int col = n0 + wn + ni * 16 + (lane & 15);
    float bias = b_ih[col] + b_hh[col];
#pragma unroll
    for (int mi = 0; mi < 4; ++mi) {
#pragma unroll
      for (int j = 0; j < 4; ++j) {
        int row = m0 + wm + mi * 16 + (lane >> 4) * 4 + j;
        gx[(size_t)row * 512 + col] = acc[mi][ni][j] + accc[mi][ni][j] * ks + bias;
      }
    }
  }
}

// ---------------- k3: persistent LSTM (f32), 1 block per batch, 512 threads = 512 gate rows
__global__ __launch_bounds__(512) void k3_lstm(
    const float* __restrict__ gx, const float* __restrict__ w_hh, float* __restrict__ out,
    int tc0, int nt, float* __restrict__ carry_h, float* __restrict__ carry_c, int first) {
  const int b = blockIdx.x;
  const int g = threadIdx.x;
  __shared__ __align__(16) float h_lds[128];
  __shared__ float gates[512];

  // w_hh row g -> 32 f32x4 registers
  f32x4 wv[32];
  const float* wr = w_hh + (size_t)g * 128;
#pragma unroll
  for (int k = 0; k < 32; ++k) wv[k] = *(const f32x4*)(wr + 4 * k);

  float cst = 0.f;
  if (g < 128) {
    h_lds[g] = first ? 0.f : carry_h[b * 128 + g];
    if (!first) cst = carry_c[b * 128 + g];
  }
  float gxn = gx[(size_t)b * 512 + g];
  __syncthreads();

  for (int t = 0; t < nt; ++t) {
    int tn = (t + 1 < nt) ? (t + 1) : t;
    float gx_next = gx[((size_t)tn * 64 + b) * 512 + g];

    f32x4 a = {0.f, 0.f, 0.f, 0.f};
    const f32x4* h4 = (const f32x4*)h_lds;
#pragma unroll
    for (int k = 0; k < 32; ++k) {
      a = vfma4(wv[k], h4[k], a);
    }
    float pre = gxn + ((a[0] + a[1]) + (a[2] + a[3]));
    float act = ((g >> 7) == 2) ? tanhf(pre) : 1.f / (1.f + expf(-pre));
    gates[g] = act;
    gxn = gx_next;
    __syncthreads();

    if (g < 128) {
      float i_ = gates[g], f_ = gates[g + 128], gg = gates[g + 256], o_ = gates[g + 384];
      cst = fmaf(f_, cst, i_ * gg);
      float h = o_ * tanhf(cst);
      h_lds[g] = h;
      out[((size_t)b * 128 + g) * T_LEN + tc0 + t] = h;
    }
    __syncthreads();
  }
  if (g < 128) {
    carry_h[b * 128 + g] = h_lds[g];
    carry_c[b * 128 + g] = cst;
  }
}

extern "C" void kernel_launch(void* const* d_in, const int* in_sizes, int n_in,
                              void* d_out, int out_size, void* d_ws, size_t ws_size,
                              hipStream_t stream) {
  const float* x    = (const float*)d_in[0];
  const float* dw_w = (const float*)d_in[1];
  const float* dw_b = (const float*)d_in[2];
  const float* bn_g = (const float*)d_in[3];
  const float* bn_b = (const float*)d_in[4];
  const float* bn_m = (const float*)d_in[5];
  const float* bn_v = (const float*)d_in[6];
  const float* pw_w = (const float*)d_in[7];
  const float* pw_b = (const float*)d_in[8];
  const float* w_ih = (const float*)d_in[9];
  const float* w_hh = (const float*)d_in[10];
  const float* b_ih = (const float*)d_in[11];
  const float* b_hh = (const float*)d_in[12];
  float* out = (float*)d_out;

  float* hpw = (float*)d_ws;                                        // 33.55 MB (chunk)
  float* gx  = (float*)((char*)d_ws + (size_t)33554432);            // 134.2 MB (chunk)
  float* ch  = (float*)((char*)d_ws + (size_t)167772160);           // 32 KB
  float* cc  = (float*)((char*)d_ws + (size_t)167804928);           // 32 KB

  for (int c = 0; c < 2; ++c) {
    int tc0 = c * T_CHUNK;
    k1_front<<<dim3(8, 64), 256, 0, stream>>>(x, dw_w, dw_b, bn_g, bn_b, bn_m, bn_v, pw_w, pw_b, hpw, tc0);
    k2_gx<<<dim3(512, 4), 256, 0, stream>>>(hpw, w_ih, b_ih, b_hh, gx);
    k3_lstm<<<64, 512, 0, stream>>>(gx, w_hh, out, tc0, T_CHUNK, ch, cc, c == 0);
  }
}